// Round 1
// baseline (253.891 us; speedup 1.0000x reference)
//
#include <hip/hip_runtime.h>
#include <hip/hip_bf16.h>

typedef __attribute__((ext_vector_type(8))) short bf16x8;   // 8 bf16 = 4 VGPRs
typedef __attribute__((ext_vector_type(4))) float f32x4;

__device__ __forceinline__ short f2bf(float v) {
    unsigned u = __builtin_bit_cast(unsigned, v);
    u += 0x7fffu + ((u >> 16) & 1u);          // round-to-nearest-even
    return (short)(u >> 16);
}

// block: 512 threads = 8 waves. One block handles (batch n, 2 rows, tap j):
//   wave -> (row within pair = wave>>2, 16-wide w-tile = wave&3)
// Each wave computes all 128 output channels of tap j for its 16 positions:
//   8 M-tiles of 16 o-channels, K=128 as 4 k-tiles of 32, via mfma_f32_16x16x32_bf16.
__global__ __launch_bounds__(512, 2)
void sconv_mfma(const float* __restrict__ x, const float* __restrict__ w,
                float* __restrict__ out) {
    __shared__ bf16x8 wfrag[8][4][64];   // [mt][kt][lane] = 32 KiB

    const int bid = blockIdx.x;
    const int j   = bid % 5;
    const int hp  = (bid / 5) % 32;
    const int n   = bid / 160;

    const int t = threadIdx.x;

    // ---- stage tap-j weights into LDS as A-fragments (bf16) ----
    // slot s = (mt,kt,lane); lane l holds W[o = mt*16 + (l&15)][c = kt*32 + (l>>4)*8 + e]
    for (int s = t; s < 2048; s += 512) {
        const int lane = s & 63;
        const int rest = s >> 6;            // 0..31
        const int mt   = rest >> 2;
        const int kt   = rest & 3;
        const int o    = mt * 16 + (lane & 15);
        const int c0   = kt * 32 + (lane >> 4) * 8;
        const float* wp = w + ((size_t)o * 128 + c0) * 5 + j;
        bf16x8 f;
        #pragma unroll
        for (int e = 0; e < 8; ++e) f[e] = f2bf(wp[e * 5]);
        wfrag[mt][kt][lane] = f;
    }
    __syncthreads();

    const int wave = t >> 6;
    const int lane = t & 63;
    const int l15  = lane & 15;
    const int lg   = lane >> 4;

    const int h    = hp * 2 + (wave >> 2);
    const int wcol = (wave & 3) * 16 + l15;      // output w position of this lane

    const int dy[5] = {-1, 0, 0, 0, 1};
    const int dx[5] = { 0,-1, 0, 1, 0};
    const int hi = h + dy[j];
    const int wi = wcol + dx[j];
    const bool valid = ((unsigned)hi < 64u) && ((unsigned)wi < 64u);
    const int hic = hi < 0 ? 0 : (hi > 63 ? 63 : hi);
    const int wic = wi < 0 ? 0 : (wi > 63 ? 63 : wi);

    // ---- gather X fragments (B operand), held in registers across M loop ----
    // lane l holds X[c = kt*32 + (l>>4)*8 + e][pos = tile + (l&15)]
    const float* xb = x + (size_t)n * 128 * 4096 + (size_t)(hic * 64 + wic);
    bf16x8 xf[4];
    #pragma unroll
    for (int kt = 0; kt < 4; ++kt) {
        const int c0 = kt * 32 + lg * 8;
        const float* xp = xb + (size_t)c0 * 4096;
        bf16x8 f;
        #pragma unroll
        for (int e = 0; e < 8; ++e) {
            float v = xp[(size_t)e * 4096];
            f[e] = f2bf(valid ? v : 0.0f);
        }
        xf[kt] = f;
    }

    // ---- MFMA: acc[mt] += Wfrag[mt][kt] * Xfrag[kt] ----
    f32x4 acc[8];
    #pragma unroll
    for (int mt = 0; mt < 8; ++mt) acc[mt] = f32x4{0.f, 0.f, 0.f, 0.f};

    #pragma unroll
    for (int kt = 0; kt < 4; ++kt) {
        #pragma unroll
        for (int mt = 0; mt < 8; ++mt) {
            acc[mt] = __builtin_amdgcn_mfma_f32_16x16x32_bf16(
                wfrag[mt][kt][lane], xf[kt], acc[mt], 0, 0, 0);
        }
    }

    // ---- epilogue: ReLU + store. D layout: col = lane&15 (pos), row = lg*4 + r ----
    float* ob = out + ((size_t)n * 640 + (size_t)j * 128) * 4096
                    + (size_t)(h * 64 + wcol);
    #pragma unroll
    for (int mt = 0; mt < 8; ++mt) {
        const int ch = mt * 16 + lg * 4;
        #pragma unroll
        for (int r = 0; r < 4; ++r) {
            float v = acc[mt][r];
            ob[(size_t)(ch + r) * 4096] = v > 0.f ? v : 0.f;
        }
    }
}

extern "C" void kernel_launch(void* const* d_in, const int* in_sizes, int n_in,
                              void* d_out, int out_size, void* d_ws, size_t ws_size,
                              hipStream_t stream) {
    const float* x = (const float*)d_in[0];   // [32,128,64,64] f32
    const float* w = (const float*)d_in[1];   // [128,128,5] f32
    float* out = (float*)d_out;               // [32,640,64,64] f32

    dim3 grid(32 * 32 * 5);   // (n, row-pair, tap)
    dim3 block(512);
    hipLaunchKernelGGL(sconv_mfma, grid, block, 0, stream, x, w, out);
}

// Round 2
// 168.192 us; speedup vs baseline: 1.5095x; 1.5095x over previous
//
#include <hip/hip_runtime.h>
#include <hip/hip_bf16.h>

typedef __attribute__((ext_vector_type(8))) short bf16x8;   // 8 bf16 = 4 VGPRs
typedef __attribute__((ext_vector_type(4))) float f32x4;

__device__ __forceinline__ short f2bf(float v) {
    unsigned u = __builtin_bit_cast(unsigned, v);
    u += 0x7fffu + ((u >> 16) & 1u);          // round-to-nearest-even
    return (short)(u >> 16);
}

// ---------------- prep: build bf16 W-fragments into d_ws ----------------
// Fragment slot (mt, kt, lane): mt = j*8 + ot (40 m-tiles of 16 channels),
// lane l holds W[o = ot*16 + (l&15)][c = kt*32 + (l>>4)*8 + e] for tap j.
// Same (lane-group, elem)->c map is used for the X (B) operand, so the
// hardware's internal k permutation cancels (verified passing in R1).
__global__ __launch_bounds__(64)
void prep_wfrag(const float* __restrict__ w, bf16x8* __restrict__ wf) {
    const int mt   = blockIdx.x >> 2;       // 0..39
    const int kt   = blockIdx.x & 3;        // 0..3
    const int lane = threadIdx.x;           // 0..63
    const int j  = mt >> 3;
    const int ot = mt & 7;
    const int o  = ot * 16 + (lane & 15);
    const int c0 = kt * 32 + (lane >> 4) * 8;
    const float* wp = w + ((size_t)o * 128 + c0) * 5 + j;
    bf16x8 f;
    #pragma unroll
    for (int e = 0; e < 8; ++e) f[e] = f2bf(wp[e * 5]);
    wf[(size_t)(mt * 4 + kt) * 64 + lane] = f;
}

// ---------------- main: one block per (n, h) row of Y ----------------
// 512 threads = 8 waves = 2 mt-halves (20 m-tiles each) x 4 pos-tiles (16 w).
// Unshifted GEMM Y[j,o](h,w) = sum_c W_j[o,c] x[c,h,w]; tap shift folded into
// the store: out[j*128+o, h-dy_j, w-dx_j] = relu(Y). The single out-of-range
// lane/row redirects to the never-written opposite edge and stores 0.
__global__ __launch_bounds__(512)
void sconv_main(const float* __restrict__ x, const bf16x8* __restrict__ wf,
                float* __restrict__ out) {
    const int bid = blockIdx.x;
    const int h = bid & 63;
    const int n = bid >> 6;

    const int t    = threadIdx.x;
    const int wave = t >> 6;
    const int lane = t & 63;
    const int mh   = wave >> 2;             // which 20 m-tiles
    const int pt   = wave & 3;              // which 16 positions
    const int l15  = lane & 15;
    const int lg   = lane >> 4;
    const int wcol = pt * 16 + l15;

    // ---- gather X fragments (B operand), all in-bounds, kept in regs ----
    const float* xb = x + (size_t)n * 128 * 4096 + (size_t)(h * 64 + wcol);
    bf16x8 xf[4];
    #pragma unroll
    for (int kt = 0; kt < 4; ++kt) {
        const int c0 = kt * 32 + lg * 8;
        const float* xp = xb + (size_t)c0 * 4096;
        bf16x8 f;
        #pragma unroll
        for (int e = 0; e < 8; ++e) f[e] = f2bf(xp[(size_t)e * 4096]);
        xf[kt] = f;
    }

    const int dyA[5] = {-1, 0, 0, 0, 1};
    const int dxA[5] = { 0,-1, 0, 1, 0};

    #pragma unroll 2
    for (int mi = 0; mi < 20; ++mi) {
        const int mt = mh * 20 + mi;
        const int j  = mt >> 3;
        const int ot = mt & 7;

        const bf16x8* afp = wf + (size_t)(mt * 4) * 64 + lane;
        f32x4 acc = {0.f, 0.f, 0.f, 0.f};
        #pragma unroll
        for (int kt = 0; kt < 4; ++kt)
            acc = __builtin_amdgcn_mfma_f32_16x16x32_bf16(afp[(size_t)kt * 64],
                                                          xf[kt], acc, 0, 0, 0);

        // shifted store with redirected zero-fill
        const int hh = h - dyA[j];
        const int ww = wcol - dxA[j];
        const bool valid = ((unsigned)hh < 64u) && ((unsigned)ww < 64u);
        const int hs = hh < 0 ? 63 : (hh > 63 ? 0 : hh);
        const int ws = ww < 0 ? 63 : (ww > 63 ? 0 : ww);

        float* ob = out + (((size_t)n * 640 + j * 128 + ot * 16 + lg * 4) * 64
                           + hs) * 64 + ws;
        #pragma unroll
        for (int r = 0; r < 4; ++r) {
            float v = valid ? acc[r] : 0.f;
            ob[(size_t)r * 4096] = v > 0.f ? v : 0.f;
        }
    }
}

// ---------------- fallback (R1 kernel) if workspace is too small ----------------
__global__ __launch_bounds__(512, 2)
void sconv_mfma(const float* __restrict__ x, const float* __restrict__ w,
                float* __restrict__ out) {
    __shared__ bf16x8 wfrag[8][4][64];
    const int bid = blockIdx.x;
    const int j   = bid % 5;
    const int hp  = (bid / 5) % 32;
    const int n   = bid / 160;
    const int t = threadIdx.x;
    for (int s = t; s < 2048; s += 512) {
        const int lane = s & 63;
        const int rest = s >> 6;
        const int mt   = rest >> 2;
        const int kt   = rest & 3;
        const int o    = mt * 16 + (lane & 15);
        const int c0   = kt * 32 + (lane >> 4) * 8;
        const float* wp = w + ((size_t)o * 128 + c0) * 5 + j;
        bf16x8 f;
        #pragma unroll
        for (int e = 0; e < 8; ++e) f[e] = f2bf(wp[e * 5]);
        wfrag[mt][kt][lane] = f;
    }
    __syncthreads();
    const int wave = t >> 6;
    const int lane = t & 63;
    const int l15  = lane & 15;
    const int lg   = lane >> 4;
    const int h    = hp * 2 + (wave >> 2);
    const int wcol = (wave & 3) * 16 + l15;
    const int dy[5] = {-1, 0, 0, 0, 1};
    const int dx[5] = { 0,-1, 0, 1, 0};
    const int hi = h + dy[j];
    const int wi = wcol + dx[j];
    const bool valid = ((unsigned)hi < 64u) && ((unsigned)wi < 64u);
    const int hic = hi < 0 ? 0 : (hi > 63 ? 63 : hi);
    const int wic = wi < 0 ? 0 : (wi > 63 ? 63 : wi);
    const float* xb = x + (size_t)n * 128 * 4096 + (size_t)(hic * 64 + wic);
    bf16x8 xf[4];
    #pragma unroll
    for (int kt = 0; kt < 4; ++kt) {
        const int c0 = kt * 32 + lg * 8;
        const float* xp = xb + (size_t)c0 * 4096;
        bf16x8 f;
        #pragma unroll
        for (int e = 0; e < 8; ++e) {
            float v = xp[(size_t)e * 4096];
            f[e] = f2bf(valid ? v : 0.0f);
        }
        xf[kt] = f;
    }
    f32x4 acc[8];
    #pragma unroll
    for (int mt = 0; mt < 8; ++mt) acc[mt] = f32x4{0.f, 0.f, 0.f, 0.f};
    #pragma unroll
    for (int kt = 0; kt < 4; ++kt)
        #pragma unroll
        for (int mt = 0; mt < 8; ++mt)
            acc[mt] = __builtin_amdgcn_mfma_f32_16x16x32_bf16(
                wfrag[mt][kt][lane], xf[kt], acc[mt], 0, 0, 0);
    float* ob = out + ((size_t)n * 640 + (size_t)j * 128) * 4096
                    + (size_t)(h * 64 + wcol);
    #pragma unroll
    for (int mt = 0; mt < 8; ++mt) {
        const int ch = mt * 16 + lg * 4;
        #pragma unroll
        for (int r = 0; r < 4; ++r) {
            float v = acc[mt][r];
            ob[(size_t)(ch + r) * 4096] = v > 0.f ? v : 0.f;
        }
    }
}

extern "C" void kernel_launch(void* const* d_in, const int* in_sizes, int n_in,
                              void* d_out, int out_size, void* d_ws, size_t ws_size,
                              hipStream_t stream) {
    const float* x = (const float*)d_in[0];   // [32,128,64,64] f32
    const float* w = (const float*)d_in[1];   // [128,128,5] f32
    float* out = (float*)d_out;               // [32,640,64,64] f32

    const size_t wf_bytes = (size_t)40 * 4 * 64 * sizeof(bf16x8);  // 160 KiB
    if (ws_size >= wf_bytes) {
        bf16x8* wf = (bf16x8*)d_ws;
        hipLaunchKernelGGL(prep_wfrag, dim3(160), dim3(64), 0, stream, w, wf);
        hipLaunchKernelGGL(sconv_main, dim3(32 * 64), dim3(512), 0, stream,
                           x, wf, out);
    } else {
        hipLaunchKernelGGL(sconv_mfma, dim3(32 * 32 * 5), dim3(512), 0, stream,
                           x, w, out);
    }
}